// Round 2
// baseline (644.222 us; speedup 1.0000x reference)
//
#include <hip/hip_runtime.h>

// Problem dims (fixed by setup_inputs): B=4096, A=2048, F=8
#define NB    4096
#define AP1   2049            // A+1 rows per sample
#define FEAT  8
#define ROWF  (AP1 * FEAT)    // 16392 floats per sample

// Native vector type: __builtin_nontemporal_load requires scalar/native-vector,
// not HIP_vector_type<float,4>.
typedef float f32x4 __attribute__((ext_vector_type(4)));

// ws layout (16 bytes, zeroed via hipMemsetAsync at the top of each launch,
// so the zeroing replays inside the captured graph):
//   ws[0] : sum over b of (pred_count - targ_count)^2
//   ws[1] : sum over valid b of per-sample mse
//   ws[2] : n_valid (as float)
//   ws[3] : finished-block counter (uint), last block computes the output

__global__ __launch_bounds__(256) void loss_fused_kernel(
        const float* __restrict__ pred,
        const float* __restrict__ targ,
        float* __restrict__ ws,
        float* __restrict__ out) {
    const int b = blockIdx.x;
    const float* pb = pred + (size_t)b * ROWF;
    const float* tb = targ + (size_t)b * ROWF;

    const float tc = tb[0];      // target count (exact small integer in fp32)
    const float pc = pb[0];      // predicted count
    const int count = (int)tc;

    // Actions region: floats [FEAT, FEAT + count*FEAT) — 16B-aligned,
    // count*FEAT divisible by 8 -> count*2 float4 chunks.
    const int nvec = count * 2;
    const f32x4* p4 = (const f32x4*)(pb + FEAT);
    const f32x4* t4 = (const f32x4*)(tb + FEAT);

    float s = 0.0f;
    int i = (int)threadIdx.x;
    const int stride = 256;

    // 4x unrolled: 8 independent non-temporal loads in flight per thread.
    // Data is streamed exactly once (537 MB footprint >> 32 MB L2) — skip
    // cache allocation.
    for (; i + 3 * stride < nvec; i += 4 * stride) {
        const f32x4 a0 = __builtin_nontemporal_load(&p4[i]);
        const f32x4 a1 = __builtin_nontemporal_load(&p4[i + stride]);
        const f32x4 a2 = __builtin_nontemporal_load(&p4[i + 2 * stride]);
        const f32x4 a3 = __builtin_nontemporal_load(&p4[i + 3 * stride]);
        const f32x4 c0 = __builtin_nontemporal_load(&t4[i]);
        const f32x4 c1 = __builtin_nontemporal_load(&t4[i + stride]);
        const f32x4 c2 = __builtin_nontemporal_load(&t4[i + 2 * stride]);
        const f32x4 c3 = __builtin_nontemporal_load(&t4[i + 3 * stride]);
        f32x4 d;
        d = a0 - c0; s += d.x * d.x + d.y * d.y + d.z * d.z + d.w * d.w;
        d = a1 - c1; s += d.x * d.x + d.y * d.y + d.z * d.z + d.w * d.w;
        d = a2 - c2; s += d.x * d.x + d.y * d.y + d.z * d.z + d.w * d.w;
        d = a3 - c3; s += d.x * d.x + d.y * d.y + d.z * d.z + d.w * d.w;
    }
    for (; i < nvec; i += stride) {
        const f32x4 a = __builtin_nontemporal_load(&p4[i]);
        const f32x4 c = __builtin_nontemporal_load(&t4[i]);
        const f32x4 d = a - c;
        s += d.x * d.x + d.y * d.y + d.z * d.z + d.w * d.w;
    }

    // block reduction
    #pragma unroll
    for (int o = 32; o > 0; o >>= 1) s += __shfl_down(s, o, 64);
    __shared__ float sm[4];
    const int wid  = threadIdx.x >> 6;
    const int lane = threadIdx.x & 63;
    if (lane == 0) sm[wid] = s;
    __syncthreads();

    if (threadIdx.x == 0) {
        const float total = sm[0] + sm[1] + sm[2] + sm[3];
        const float d = pc - tc;
        const bool valid = (count > 0);

        // Device-scope accumulation (3 addresses, 4096 adds each — trivial
        // contention; atomics resolve at L2 point of coherence).
        atomicAdd(&ws[0], d * d);
        if (valid) {
            atomicAdd(&ws[1], total / (float)(count * FEAT));
            atomicAdd(&ws[2], 1.0f);
        }
        __threadfence();
        const unsigned old = atomicAdd((unsigned*)(ws + 3), 1u);
        if (old == NB - 1) {
            // All other blocks' adds happened-before their counter bump
            // (threadfence), and atomic RMW reads the coherent value at the
            // atomic unit — read via add-zero.
            const float count_sum = atomicAdd(&ws[0], 0.0f);
            const float mse_sum   = atomicAdd(&ws[1], 0.0f);
            const float nv        = atomicAdd(&ws[2], 0.0f);
            const float count_loss = count_sum * (1.0f / (float)NB);
            const float atl = (nv > 0.0f) ? (mse_sum / nv) : 0.0f;
            out[0] = count_loss + 2.0f * atl;  // W_ACTION_COUNT=1, W_ACTION_TENSOR=2
        }
    }
}

extern "C" void kernel_launch(void* const* d_in, const int* in_sizes, int n_in,
                              void* d_out, int out_size, void* d_ws, size_t ws_size,
                              hipStream_t stream) {
    const float* pred = (const float*)d_in[0];
    const float* targ = (const float*)d_in[1];
    float* out = (float*)d_out;
    float* ws  = (float*)d_ws;

    // Zero the 4 accumulator/counter slots; replays inside the graph.
    (void)hipMemsetAsync(ws, 0, 16, stream);
    loss_fused_kernel<<<NB, 256, 0, stream>>>(pred, targ, ws, out);
}